// Round 4
// baseline (313.872 us; speedup 1.0000x reference)
//
#include <hip/hip_runtime.h>
#include <hip/hip_bf16.h>
#include <math.h>

#define B_ 64
#define S_ 512
#define VEC_ 768
#define H_ 256
#define M_ (B_*S_)   // 32768

typedef float floatx4 __attribute__((ext_vector_type(4)));
typedef __bf16 bf16x8 __attribute__((ext_vector_type(8)));
typedef __bf16 bf16x4 __attribute__((ext_vector_type(4)));

// prep: cast mlp_w (f32 [256,768]) -> bf16, zero doc-sum accumulators
__global__ __launch_bounds__(256) void prep_kernel(
    const float* __restrict__ mlp_w, __bf16* __restrict__ wbf, float* __restrict__ sums)
{
  const int bid = blockIdx.x;
  if (bid < 192) {
    const int i = bid * 256 + threadIdx.x;           // float4 index, 49152 total
    const float4 v = ((const float4*)mlp_w)[i];
    bf16x4 b = { (__bf16)v.x, (__bf16)v.y, (__bf16)v.z, (__bf16)v.w };
    *(bf16x4*)&wbf[(size_t)i * 4] = b;
  } else {
    const int i = (bid - 192) * 256 + threadIdx.x;   // 8192 float4 = 2*64*256 f32
    ((float4*)sums)[i] = make_float4(0.f, 0.f, 0.f, 0.f);
  }
}

// ---------------- GEMM: BK=128, page-friendly 512B/row reads ----------------
// Theory: BK=32 read 128B per A-row per step at 3KB stride -> DRAM page-bound
// (~2 TB/s across 3 different schedules). BK=128 reads 512B contiguous per row.
// Reg-staged (global->VGPR->cvt->ds_write), raw s_barrier + lgkmcnt only
// (round-3 machinery, verified correct). 2 x 64KB LDS buffers, 6 K-steps.
// LDS layout (A and B identical): row = 256B (128 bf16), 16 slots of 16B,
// phys_slot = logical ^ (row & 7)  -> 8 lanes per 4-bank group on both
// ds_write_b128 and ds_read_b128 = conflict-free minimum.
#define ABYTES_ 32768
#define BUFSZ_  65536
#define LDSB_   131072

__device__ __forceinline__ bf16x8 cvt8(float4 a, float4 b) {
  bf16x8 v;
  v[0] = (__bf16)a.x; v[1] = (__bf16)a.y; v[2] = (__bf16)a.z; v[3] = (__bf16)a.w;
  v[4] = (__bf16)b.x; v[5] = (__bf16)b.y; v[6] = (__bf16)b.z; v[7] = (__bf16)b.w;
  return v;
}

// load tile kt into regs: A 16 float4 (512B contiguous per 2-thread row pair),
// B 8 bf16x8 (256B contiguous per row pair)
#define LOADT(kk)                                                             \
  {                                                                           \
    const float*  pA_ = Aload + (kk);                                         \
    const __bf16* pB_ = Bload + (kk);                                         \
    _Pragma("unroll")                                                         \
    for (int j_ = 0; j_ < 16; j_++) aR[j_] = *(const float4*)(pA_ + j_ * 4);  \
    _Pragma("unroll")                                                         \
    for (int j_ = 0; j_ < 8; j_++)  bR[j_] = *(const bf16x8*)(pB_ + j_ * 8);  \
  }

// publish regs to LDS buffer at byte offset bufbase (8+8 ds_write_b128)
#define DSWRITE(bufbase)                                                      \
  {                                                                           \
    _Pragma("unroll")                                                         \
    for (int j_ = 0; j_ < 8; j_++) {                                          \
      const int phys = (shalf * 8 + j_) ^ (srow & 7);                         \
      *(bf16x8*)(smem + (bufbase) + srow * 256 + phys * 16) =                 \
          cvt8(aR[2 * j_], aR[2 * j_ + 1]);                                   \
    }                                                                         \
    _Pragma("unroll")                                                         \
    for (int j_ = 0; j_ < 8; j_++) {                                          \
      const int phys = (shalf * 8 + j_) ^ (srow & 7);                         \
      *(bf16x8*)(smem + (bufbase) + ABYTES_ + srow * 256 + phys * 16) = bR[j_]; \
    }                                                                         \
  }

// 4 sub-K of 32: fragment reads (swizzled) + 16 MFMA each
#define COMPUTE(bufbase)                                                      \
  {                                                                           \
    _Pragma("unroll")                                                         \
    for (int ks = 0; ks < 4; ks++) {                                          \
      const int slot = ((ks * 4 + q) ^ (c & 7)) * 16;                         \
      bf16x8 af[4], bfr[4];                                                   \
      _Pragma("unroll")                                                       \
      for (int i = 0; i < 4; i++)                                             \
        af[i] = *(const bf16x8*)(smem + (bufbase) + (wm + i * 16 + c) * 256 + slot); \
      _Pragma("unroll")                                                       \
      for (int j = 0; j < 4; j++)                                             \
        bfr[j] = *(const bf16x8*)(smem + (bufbase) + ABYTES_ + (wn + j * 16 + c) * 256 + slot); \
      _Pragma("unroll")                                                       \
      for (int i = 0; i < 4; i++)                                             \
        _Pragma("unroll")                                                     \
        for (int j = 0; j < 4; j++)                                           \
          acc[i][j] = __builtin_amdgcn_mfma_f32_16x16x32_bf16(af[i], bfr[j],  \
                                                              acc[i][j], 0, 0, 0); \
    }                                                                         \
  }

__global__ __launch_bounds__(256, 2) void gemm_doc_kernel(
    const float* __restrict__ out1, const float* __restrict__ out2,
    const __bf16* __restrict__ wbf, const float* __restrict__ mlp_b,
    __bf16* __restrict__ o1, float* __restrict__ sum1, float* __restrict__ sum2)
{
  __shared__ __align__(16) char smem[LDSB_];

  const int tensor = blockIdx.z;
  const float* __restrict__ A = tensor ? out2 : out1;
  float* __restrict__ dsum = tensor ? sum2 : sum1;

  const int n0 = blockIdx.x * 128;
  const int m0 = blockIdx.y * 128;
  const int bidx = m0 >> 9;  // 512 rows per doc; tiles never straddle docs

  const int t = threadIdx.x;
  const int lane = t & 63;
  const int wave = t >> 6;
  const int q = lane >> 4;
  const int c = lane & 15;
  const int wm = (wave >> 1) * 64;
  const int wn = (wave & 1) * 64;

  // staging: 2 threads per row; thread t owns row t>>1, half t&1 (A: 64 f32 =
  // 256B contiguous; B: 64 bf16 = 128B contiguous)
  const int srow  = t >> 1;
  const int shalf = t & 1;
  const float*  Aload = A   + (size_t)(m0 + srow) * VEC_ + shalf * 64;
  const __bf16* Bload = wbf + (size_t)(n0 + srow) * VEC_ + shalf * 64;

  floatx4 acc[4][4];
#pragma unroll
  for (int i = 0; i < 4; i++)
#pragma unroll
    for (int j = 0; j < 4; j++)
      acc[i][j] = (floatx4){0.f, 0.f, 0.f, 0.f};

  float4 aR[16];
  bf16x8 bR[8];

  LOADT(0)   // prologue: tile 0 -> regs

  int bufb = 0;
#pragma unroll 1
  for (int kt = 0; kt < 6; ++kt) {
    DSWRITE(bufb)                 // auto counted-vmcnt on tile kt's regs only
    if (kt < 5) LOADT((kt + 1) * 128)   // refill regs; in flight during compute
    asm volatile("s_waitcnt lgkmcnt(0)" ::: "memory");
    __builtin_amdgcn_s_barrier();
    COMPUTE(bufb)
    bufb ^= BUFSZ_;
  }

  // epilogue: bias + relu, store bf16 (tensor 0), column sums -> atomicAdd doc sums
#pragma unroll
  for (int j = 0; j < 4; j++) {
    const int n = n0 + wn + j * 16 + c;
    const float bias = mlp_b[n];
    float colsum = 0.f;
#pragma unroll
    for (int i = 0; i < 4; i++) {
      const int mbase = m0 + wm + i * 16 + q * 4;
#pragma unroll
      for (int r = 0; r < 4; r++) {
        float v = acc[i][j][r] + bias;
        v = fmaxf(v, 0.f);
        colsum += v;
        if (tensor == 0) o1[(size_t)(mbase + r) * H_ + n] = (__bf16)v;
      }
    }
    colsum += __shfl_down(colsum, 32);
    colsum += __shfl_down(colsum, 16);
    if (lane < 16)
      atomicAdd(&dsum[bidx * H_ + n0 + wn + j * 16 + lane], colsum);
  }
}

// logits: one s-row per wave. grid (129, B): s = bx*4+wave, rows 0..511 from o1,
// row 512 from o1_doc. lg[b,s] = dot(o1_row, o2_doc)
__global__ __launch_bounds__(256) void logits_kernel(
    const __bf16* __restrict__ o1, const float* __restrict__ sum1,
    const float* __restrict__ sum2, float* __restrict__ lg)
{
  const int b = blockIdx.y;
  const int t = threadIdx.x, lane = t & 63, wave = t >> 6;
  const int s = blockIdx.x * 4 + wave;
  if (s > 512) return;
  const float sc = 1.f / 512.f;
  const float4 w4 = ((const float4*)&sum2[b * H_])[lane];
  float p;
  if (s < 512) {
    const bf16x4 x = ((const bf16x4*)&o1[((size_t)b * S_ + s) * H_])[lane];
    p = ((float)x[0] * w4.x + (float)x[1] * w4.y +
         (float)x[2] * w4.z + (float)x[3] * w4.w) * sc;
  } else {
    const float4 x = ((const float4*)&sum1[b * H_])[lane];
    p = (x.x * w4.x + x.y * w4.y + x.z * w4.z + x.w * w4.w) * sc * sc;
  }
  p += __shfl_down(p, 32); p += __shfl_down(p, 16); p += __shfl_down(p, 8);
  p += __shfl_down(p, 4);  p += __shfl_down(p, 2);  p += __shfl_down(p, 1);
  if (lane == 0) lg[b * 513 + s] = p;
}

// fused: MLP head (row 512 of att) + softmax over 513 logits (rows 0..511)
__global__ __launch_bounds__(256) void softmax_head_kernel(
    const float* __restrict__ lg, const float* __restrict__ sum1, const float* __restrict__ sum2,
    const float* __restrict__ fd_w, const float* __restrict__ fd_b,
    const float* __restrict__ ff_w, const float* __restrict__ ff_b,
    float* __restrict__ out)
{
  const int b = blockIdx.x, t = threadIdx.x, lane = t & 63, wave = t >> 6;
  __shared__ __align__(16) float dc[512];
  __shared__ float sl[513];
  __shared__ float red[4], r1[4], r2[4];

  // --- head: h = relu(fd_w @ cat(o1_doc,o2_doc) + fd_b); out[512,b] = sigmoid(ff_w.h + ff_b)
  dc[t]       = sum1[b * H_ + t] * (1.f / 512.f);
  dc[t + 256] = sum2[b * H_ + t] * (1.f / 512.f);
  for (int i = t; i < 513; i += 256) sl[i] = lg[b * 513 + i];
  __syncthreads();
  const float4* wrow = (const float4*)&fd_w[(size_t)t * 512];
  const float4* dc4  = (const float4*)dc;
  float a0 = 0.f, a1 = 0.f;
#pragma unroll 8
  for (int k = 0; k < 128; k += 2) {
    const float4 w0 = wrow[k],     d0 = dc4[k];
    const float4 w1 = wrow[k + 1], d1 = dc4[k + 1];
    a0 += w0.x * d0.x + w0.y * d0.y + w0.z * d0.z + w0.w * d0.w;
    a1 += w1.x * d1.x + w1.y * d1.y + w1.z * d1.z + w1.w * d1.w;
  }
  const float h = fmaxf(a0 + a1 + fd_b[t], 0.f);
  float part = ff_w[t] * h;
  part += __shfl_down(part, 32); part += __shfl_down(part, 16);
  part += __shfl_down(part, 8);  part += __shfl_down(part, 4);
  part += __shfl_down(part, 2);  part += __shfl_down(part, 1);
  if (lane == 0) red[wave] = part;

  // --- softmax over sl[0..512]
  float m = -1e30f;
  for (int i = t; i < 513; i += 256) m = fmaxf(m, sl[i]);
  m = fmaxf(m, __shfl_down(m, 32)); m = fmaxf(m, __shfl_down(m, 16));
  m = fmaxf(m, __shfl_down(m, 8));  m = fmaxf(m, __shfl_down(m, 4));
  m = fmaxf(m, __shfl_down(m, 2));  m = fmaxf(m, __shfl_down(m, 1));
  if (lane == 0) r1[wave] = m;
  __syncthreads();
  m = fmaxf(fmaxf(r1[0], r1[1]), fmaxf(r1[2], r1[3]));
  float psum = 0.f;
  for (int i = t; i < 513; i += 256) { const float e = expf(sl[i] - m); sl[i] = e; psum += e; }
  psum += __shfl_down(psum, 32); psum += __shfl_down(psum, 16); psum += __shfl_down(psum, 8);
  psum += __shfl_down(psum, 4);  psum += __shfl_down(psum, 2);  psum += __shfl_down(psum, 1);
  if (lane == 0) r2[wave] = psum;
  __syncthreads();
  const float inv = 1.f / (r2[0] + r2[1] + r2[2] + r2[3]);
  for (int s = t; s < 512; s += 256) out[s * 64 + b] = sl[s] * inv;
  if (t == 0) {
    const float tot = red[0] + red[1] + red[2] + red[3] + ff_b[0];
    out[(size_t)512 * 64 + b] = 1.f / (1.f + expf(-tot));
  }
}

extern "C" void kernel_launch(void* const* d_in, const int* in_sizes, int n_in,
                              void* d_out, int out_size, void* d_ws, size_t ws_size,
                              hipStream_t stream) {
  const float* out1  = (const float*)d_in[0];
  const float* out2  = (const float*)d_in[1];
  const float* mlp_w = (const float*)d_in[2];
  const float* mlp_b = (const float*)d_in[3];
  const float* fd_w  = (const float*)d_in[4];
  const float* fd_b  = (const float*)d_in[5];
  const float* ff_w  = (const float*)d_in[6];
  const float* ff_b  = (const float*)d_in[7];
  float* out = (float*)d_out;

  __bf16* o1  = (__bf16*)d_ws;                       // 32768*256 bf16 = 16.78 MB
  __bf16* wbf = o1 + (size_t)M_ * H_;                // 256*768 bf16
  float*  s1  = (float*)(wbf + (size_t)H_ * VEC_);   // 64*256 f32
  float*  s2  = s1 + B_ * H_;                        // 64*256 f32
  float*  lgw = s2 + B_ * H_;                        // 64*513 f32

  prep_kernel<<<224, 256, 0, stream>>>(mlp_w, wbf, s1);
  gemm_doc_kernel<<<dim3(2, 256, 2), 256, 0, stream>>>(out1, out2, wbf, mlp_b, o1, s1, s2);
  logits_kernel<<<dim3(129, B_), 256, 0, stream>>>(o1, s1, s2, lgw);
  softmax_head_kernel<<<B_, 256, 0, stream>>>(lgw, s1, s2, fd_w, fd_b, ff_w, ff_b, out);
}

// Round 5
// 288.193 us; speedup vs baseline: 1.0891x; 1.0891x over previous
//
#include <hip/hip_runtime.h>
#include <hip/hip_bf16.h>
#include <math.h>

#define B_ 64
#define S_ 512
#define VEC_ 768
#define H_ 256
#define M_ (B_*S_)   // 32768

typedef float floatx4 __attribute__((ext_vector_type(4)));
typedef __bf16 bf16x8 __attribute__((ext_vector_type(8)));
typedef __bf16 bf16x4 __attribute__((ext_vector_type(4)));

// prep: cast mlp_w (f32 [256,768]) -> bf16, zero doc-sum accumulators
__global__ __launch_bounds__(256) void prep_kernel(
    const float* __restrict__ mlp_w, __bf16* __restrict__ wbf, float* __restrict__ sums)
{
  const int bid = blockIdx.x;
  if (bid < 192) {
    const int i = bid * 256 + threadIdx.x;           // float4 index, 49152 total
    const float4 v = ((const float4*)mlp_w)[i];
    bf16x4 b = { (__bf16)v.x, (__bf16)v.y, (__bf16)v.z, (__bf16)v.w };
    *(bf16x4*)&wbf[(size_t)i * 4] = b;
  } else {
    const int i = (bid - 192) * 256 + threadIdx.x;   // 8192 float4 = 2*64*256 f32
    ((float4*)sums)[i] = make_float4(0.f, 0.f, 0.f, 0.f);
  }
}

// ---------------- GEMM: A direct global->reg, B-only LDS ----------------
// Diagnosis r0-r4: every barrier-per-K-step LDS schedule pins at 1.6-2.2 TB/s
// (bursty load issue, lockstep waves). Fix: decouple the HBM stream from sync.
// Each wave owns a private 16-row M-strip; A-fragments load straight into regs
// (lane l&15 = row, l>>4 = k-slot — the MFMA A layout), 2-steps-ahead prefetch,
// NEVER gated by a barrier. Only B (L2-resident wbf) goes through LDS:
// N=256 full, K-chunks of 128, double-buffered 2x64KB, barrier once per 4
// K-steps, gated only by L2-fast B loads. A is read EXACTLY once from HBM.
// B LDS: row n = 256B (16 slots of 16B), phys_slot = s ^ (n&7) both sides.
#define CHUNKB_ 65536

__device__ __forceinline__ bf16x8 cvt8(float4 a, float4 b) {
  bf16x8 v;
  v[0] = (__bf16)a.x; v[1] = (__bf16)a.y; v[2] = (__bf16)a.z; v[3] = (__bf16)a.w;
  v[4] = (__bf16)b.x; v[5] = (__bf16)b.y; v[6] = (__bf16)b.z; v[7] = (__bf16)b.w;
  return v;
}

__global__ __launch_bounds__(512, 2) void gemm_doc_kernel(
    const float* __restrict__ out1, const float* __restrict__ out2,
    const __bf16* __restrict__ wbf, const float* __restrict__ mlp_b,
    __bf16* __restrict__ o1, float* __restrict__ sum1, float* __restrict__ sum2)
{
  __shared__ __align__(16) char smem[2 * CHUNKB_];

  const int tensor = blockIdx.y;
  const float* __restrict__ A = tensor ? out2 : out1;
  float* __restrict__ dsum = tensor ? sum2 : sum1;

  const int m0 = blockIdx.x * 128;          // 128 rows per block, 256 m-tiles
  const int bidx = blockIdx.x >> 2;         // doc = 512 rows = 4 blocks
  const int t = threadIdx.x;
  const int lane = t & 63;
  const int wave = t >> 6;                  // 8 waves, wave owns rows wave*16..+16
  const int q = lane >> 4;
  const int c = lane & 15;

  // A fragment source: row = m0 + wave*16 + c, k-slot base = q*8
  const float* Ap = A + (size_t)(m0 + wave * 16 + c) * VEC_ + q * 8;

  // B staging: thread t owns LDS row t>>1 (n-index), half t&1 (8 x 16B slots)
  const int brow = t >> 1, bh = t & 1;
  const __bf16* Bsrc = wbf + (size_t)brow * VEC_ + bh * 64;
  char* Bdst = smem + brow * 256;

  floatx4 acc[16];
#pragma unroll
  for (int j = 0; j < 16; j++) acc[j] = (floatx4){0.f, 0.f, 0.f, 0.f};

  float4 aR[3][2];   // 3-slot rotation, all indices compile-time literals
  bf16x8 sR[8];      // B-stage regs (one chunk = 8 x 16B per thread)

#define ALOAD(st) {                                                           \
    aR[(st) % 3][0] = *(const float4*)(Ap + (st) * 32);                       \
    aR[(st) % 3][1] = *(const float4*)(Ap + (st) * 32 + 4); }

#define BLOAD(kc) { _Pragma("unroll")                                         \
    for (int i_ = 0; i_ < 8; i_++)                                            \
      sR[i_] = *(const bf16x8*)(Bsrc + (kc) * 128 + i_ * 8); }

#define BWRITE(kc) { _Pragma("unroll")                                        \
    for (int i_ = 0; i_ < 8; i_++)                                            \
      *(bf16x8*)(Bdst + ((kc) & 1) * CHUNKB_ +                                \
                 (((bh * 8 + i_) ^ (brow & 7)) * 16)) = sR[i_]; }

  // one K-step of 32: prefetch A(st+2), cvt A(st), 16 swizzled ds_read, 16 MFMA
#define KSTEP(st) {                                                           \
    if ((st) + 2 < 24) ALOAD((st) + 2)                                        \
    const bf16x8 af = cvt8(aR[(st) % 3][0], aR[(st) % 3][1]);                 \
    const char* bb = smem + (((st) >> 2) & 1) * CHUNKB_ + c * 256 +           \
                     (((((st) & 3) * 4 + q) ^ (c & 7)) * 16);                 \
    bf16x8 bfr[8];                                                            \
    _Pragma("unroll")                                                         \
    for (int j = 0; j < 8; j++) bfr[j] = *(const bf16x8*)(bb + j * 4096);     \
    _Pragma("unroll")                                                         \
    for (int j = 0; j < 8; j++)                                               \
      acc[j] = __builtin_amdgcn_mfma_f32_16x16x32_bf16(af, bfr[j], acc[j], 0, 0, 0); \
    _Pragma("unroll")                                                         \
    for (int j = 0; j < 8; j++) bfr[j] = *(const bf16x8*)(bb + 32768 + j * 4096); \
    _Pragma("unroll")                                                         \
    for (int j = 0; j < 8; j++)                                               \
      acc[8 + j] = __builtin_amdgcn_mfma_f32_16x16x32_bf16(af, bfr[j], acc[8 + j], 0, 0, 0); \
  }

  // chunk boundary: publish next B chunk, refill stage regs, raw barrier.
  // lgkmcnt-only (NO vmcnt drain): A-loads stay in flight across barriers.
#define BOUNDARY(cn) {                                                        \
    BWRITE((cn) + 1)                                                          \
    if ((cn) < 4) BLOAD((cn) + 2)                                             \
    asm volatile("s_waitcnt lgkmcnt(0)" ::: "memory");                        \
    __builtin_amdgcn_s_barrier(); }

  // prologue
  ALOAD(0) ALOAD(1)
  BLOAD(0)
  BWRITE(0)
  BLOAD(1)
  asm volatile("s_waitcnt lgkmcnt(0)" ::: "memory");
  __builtin_amdgcn_s_barrier();

  KSTEP(0)  KSTEP(1)  KSTEP(2)  KSTEP(3)  BOUNDARY(0)
  KSTEP(4)  KSTEP(5)  KSTEP(6)  KSTEP(7)  BOUNDARY(1)
  KSTEP(8)  KSTEP(9)  KSTEP(10) KSTEP(11) BOUNDARY(2)
  KSTEP(12) KSTEP(13) KSTEP(14) KSTEP(15) BOUNDARY(3)
  KSTEP(16) KSTEP(17) KSTEP(18) KSTEP(19) BOUNDARY(4)
  KSTEP(20) KSTEP(21) KSTEP(22) KSTEP(23)

#undef ALOAD
#undef BLOAD
#undef BWRITE
#undef KSTEP
#undef BOUNDARY

  // epilogue: bias + relu, store bf16 (tensor 0), column sums -> atomicAdd
#pragma unroll
  for (int j = 0; j < 16; j++) {
    const int n = j * 16 + c;
    const float bias = mlp_b[n];
    float colsum = 0.f;
    const int mb = m0 + wave * 16 + q * 4;
#pragma unroll
    for (int r = 0; r < 4; r++) {
      float v = acc[j][r] + bias;
      v = fmaxf(v, 0.f);
      colsum += v;
      if (tensor == 0) o1[(size_t)(mb + r) * H_ + n] = (__bf16)v;
    }
    colsum += __shfl_down(colsum, 32);
    colsum += __shfl_down(colsum, 16);
    if (lane < 16)
      atomicAdd(&dsum[bidx * H_ + j * 16 + lane], colsum);
  }
}

// logits: one s-row per wave. grid (129, B): s = bx*4+wave, rows 0..511 from o1,
// row 512 from o1_doc. lg[b,s] = dot(o1_row, o2_doc)
__global__ __launch_bounds__(256) void logits_kernel(
    const __bf16* __restrict__ o1, const float* __restrict__ sum1,
    const float* __restrict__ sum2, float* __restrict__ lg)
{
  const int b = blockIdx.y;
  const int t = threadIdx.x, lane = t & 63, wave = t >> 6;
  const int s = blockIdx.x * 4 + wave;
  if (s > 512) return;
  const float sc = 1.f / 512.f;
  const float4 w4 = ((const float4*)&sum2[b * H_])[lane];
  float p;
  if (s < 512) {
    const bf16x4 x = ((const bf16x4*)&o1[((size_t)b * S_ + s) * H_])[lane];
    p = ((float)x[0] * w4.x + (float)x[1] * w4.y +
         (float)x[2] * w4.z + (float)x[3] * w4.w) * sc;
  } else {
    const float4 x = ((const float4*)&sum1[b * H_])[lane];
    p = (x.x * w4.x + x.y * w4.y + x.z * w4.z + x.w * w4.w) * sc * sc;
  }
  p += __shfl_down(p, 32); p += __shfl_down(p, 16); p += __shfl_down(p, 8);
  p += __shfl_down(p, 4);  p += __shfl_down(p, 2);  p += __shfl_down(p, 1);
  if (lane == 0) lg[b * 513 + s] = p;
}

// fused: MLP head (row 512 of att) + softmax over 513 logits (rows 0..511)
__global__ __launch_bounds__(256) void softmax_head_kernel(
    const float* __restrict__ lg, const float* __restrict__ sum1, const float* __restrict__ sum2,
    const float* __restrict__ fd_w, const float* __restrict__ fd_b,
    const float* __restrict__ ff_w, const float* __restrict__ ff_b,
    float* __restrict__ out)
{
  const int b = blockIdx.x, t = threadIdx.x, lane = t & 63, wave = t >> 6;
  __shared__ __align__(16) float dc[512];
  __shared__ float sl[513];
  __shared__ float red[4], r1[4], r2[4];

  // --- head: h = relu(fd_w @ cat(o1_doc,o2_doc) + fd_b); out[512,b] = sigmoid(ff_w.h + ff_b)
  dc[t]       = sum1[b * H_ + t] * (1.f / 512.f);
  dc[t + 256] = sum2[b * H_ + t] * (1.f / 512.f);
  for (int i = t; i < 513; i += 256) sl[i] = lg[b * 513 + i];
  __syncthreads();
  const float4* wrow = (const float4*)&fd_w[(size_t)t * 512];
  const float4* dc4  = (const float4*)dc;
  float a0 = 0.f, a1 = 0.f;
#pragma unroll 8
  for (int k = 0; k < 128; k += 2) {
    const float4 w0 = wrow[k],     d0 = dc4[k];
    const float4 w1 = wrow[k + 1], d1 = dc4[k + 1];
    a0 += w0.x * d0.x + w0.y * d0.y + w0.z * d0.z + w0.w * d0.w;
    a1 += w1.x * d1.x + w1.y * d1.y + w1.z * d1.z + w1.w * d1.w;
  }
  const float h = fmaxf(a0 + a1 + fd_b[t], 0.f);
  float part = ff_w[t] * h;
  part += __shfl_down(part, 32); part += __shfl_down(part, 16);
  part += __shfl_down(part, 8);  part += __shfl_down(part, 4);
  part += __shfl_down(part, 2);  part += __shfl_down(part, 1);
  if (lane == 0) red[wave] = part;

  // --- softmax over sl[0..512]
  float m = -1e30f;
  for (int i = t; i < 513; i += 256) m = fmaxf(m, sl[i]);
  m = fmaxf(m, __shfl_down(m, 32)); m = fmaxf(m, __shfl_down(m, 16));
  m = fmaxf(m, __shfl_down(m, 8));  m = fmaxf(m, __shfl_down(m, 4));
  m = fmaxf(m, __shfl_down(m, 2));  m = fmaxf(m, __shfl_down(m, 1));
  if (lane == 0) r1[wave] = m;
  __syncthreads();
  m = fmaxf(fmaxf(r1[0], r1[1]), fmaxf(r1[2], r1[3]));
  float psum = 0.f;
  for (int i = t; i < 513; i += 256) { const float e = expf(sl[i] - m); sl[i] = e; psum += e; }
  psum += __shfl_down(psum, 32); psum += __shfl_down(psum, 16); psum += __shfl_down(psum, 8);
  psum += __shfl_down(psum, 4);  psum += __shfl_down(psum, 2);  psum += __shfl_down(psum, 1);
  if (lane == 0) r2[wave] = psum;
  __syncthreads();
  const float inv = 1.f / (r2[0] + r2[1] + r2[2] + r2[3]);
  for (int s = t; s < 512; s += 256) out[s * 64 + b] = sl[s] * inv;
  if (t == 0) {
    const float tot = red[0] + red[1] + red[2] + red[3] + ff_b[0];
    out[(size_t)512 * 64 + b] = 1.f / (1.f + expf(-tot));
  }
}

extern "C" void kernel_launch(void* const* d_in, const int* in_sizes, int n_in,
                              void* d_out, int out_size, void* d_ws, size_t ws_size,
                              hipStream_t stream) {
  const float* out1  = (const float*)d_in[0];
  const float* out2  = (const float*)d_in[1];
  const float* mlp_w = (const float*)d_in[2];
  const float* mlp_b = (const float*)d_in[3];
  const float* fd_w  = (const float*)d_in[4];
  const float* fd_b  = (const float*)d_in[5];
  const float* ff_w  = (const float*)d_in[6];
  const float* ff_b  = (const float*)d_in[7];
  float* out = (float*)d_out;

  __bf16* o1  = (__bf16*)d_ws;                       // 32768*256 bf16 = 16.78 MB
  __bf16* wbf = o1 + (size_t)M_ * H_;                // 256*768 bf16
  float*  s1  = (float*)(wbf + (size_t)H_ * VEC_);   // 64*256 f32
  float*  s2  = s1 + B_ * H_;                        // 64*256 f32
  float*  lgw = s2 + B_ * H_;                        // 64*513 f32

  prep_kernel<<<224, 256, 0, stream>>>(mlp_w, wbf, s1);
  gemm_doc_kernel<<<dim3(256, 2), 512, 0, stream>>>(out1, out2, wbf, mlp_b, o1, s1, s2);
  logits_kernel<<<dim3(129, B_), 256, 0, stream>>>(o1, s1, s2, lgw);
  softmax_head_kernel<<<B_, 256, 0, stream>>>(lgw, s1, s2, fd_w, fd_b, ff_w, ff_b, out);
}

// Round 6
// 286.763 us; speedup vs baseline: 1.0945x; 1.0050x over previous
//
#include <hip/hip_runtime.h>
#include <hip/hip_bf16.h>
#include <math.h>

#define B_ 64
#define S_ 512
#define VEC_ 768
#define H_ 256
#define M_ (B_*S_)   // 32768

typedef float floatx4 __attribute__((ext_vector_type(4)));
typedef __bf16 bf16x8 __attribute__((ext_vector_type(8)));
typedef __bf16 bf16x4 __attribute__((ext_vector_type(4)));

// prep: cast mlp_w (f32 [256,768]) -> bf16, zero doc-sum accumulators
__global__ __launch_bounds__(256) void prep_kernel(
    const float* __restrict__ mlp_w, __bf16* __restrict__ wbf, float* __restrict__ sums)
{
  const int bid = blockIdx.x;
  if (bid < 192) {
    const int i = bid * 256 + threadIdx.x;           // float4 index, 49152 total
    const float4 v = ((const float4*)mlp_w)[i];
    bf16x4 b = { (__bf16)v.x, (__bf16)v.y, (__bf16)v.z, (__bf16)v.w };
    *(bf16x4*)&wbf[(size_t)i * 4] = b;
  } else {
    const int i = (bid - 192) * 256 + threadIdx.x;   // 8192 float4 = 2*64*256 f32
    ((float4*)sums)[i] = make_float4(0.f, 0.f, 0.f, 0.f);
  }
}

// ---------------- GEMM: r5 structure at 2x occupancy ----------------
// r0-r5 post-mortem: all five schedules plateau at ~2 TB/s delivered; the
// shared invariant is ~8 waves/CU. Latency-hiding needs ~25KB in flight/CU;
// 8 waves with <=4KB each can't sustain it. Fix: 1024-thread blocks (16
// waves/CU, 1 block/CU exactly, 256 blocks total), wave still owns a private
// 16-row strip, A-prefetch depth 3 (6KB/wave in flight). A never touches LDS
// and is never gated by a barrier (lgkm-only waits). B (L2-resident) staged
// in LDS, K-chunks of 128, double-buffered 2x64KB, read ONCE per block.
#define CHUNKB_ 65536

__device__ __forceinline__ bf16x8 cvt8(float4 a, float4 b) {
  bf16x8 v;
  v[0] = (__bf16)a.x; v[1] = (__bf16)a.y; v[2] = (__bf16)a.z; v[3] = (__bf16)a.w;
  v[4] = (__bf16)b.x; v[5] = (__bf16)b.y; v[6] = (__bf16)b.z; v[7] = (__bf16)b.w;
  return v;
}

__global__ __launch_bounds__(1024, 4) void gemm_doc_kernel(
    const float* __restrict__ out1, const float* __restrict__ out2,
    const __bf16* __restrict__ wbf, const float* __restrict__ mlp_b,
    __bf16* __restrict__ o1, float* __restrict__ sum1, float* __restrict__ sum2)
{
  __shared__ __align__(16) char smem[2 * CHUNKB_];

  const int tensor = blockIdx.y;
  const float* __restrict__ A = tensor ? out2 : out1;
  float* __restrict__ dsum = tensor ? sum2 : sum1;

  const int m0 = blockIdx.x * 256;          // 256 rows per block, 128 m-tiles
  const int bidx = blockIdx.x >> 1;         // doc = 512 rows = 2 blocks
  const int t = threadIdx.x;
  const int lane = t & 63;
  const int wave = t >> 6;                  // 16 waves; wave owns rows wave*16..+16
  const int q = lane >> 4;
  const int c = lane & 15;

  // A fragment source: row = m0 + wave*16 + c, k-slot base = q*8 (MFMA A layout)
  const float* Ap = A + (size_t)(m0 + wave * 16 + c) * VEC_ + q * 8;

  // B staging: thread t owns LDS row t>>2 (n-index), quarter t&3 (4 x 16B slots)
  const int brow = t >> 2, bq = t & 3;
  const __bf16* Bsrc = wbf + (size_t)brow * VEC_ + bq * 32;
  char* Bdst = smem + brow * 256;

  floatx4 acc[16];
#pragma unroll
  for (int j = 0; j < 16; j++) acc[j] = (floatx4){0.f, 0.f, 0.f, 0.f};

  float4 aR[4][2];   // 4-slot rotation (depth-3 prefetch), literal indices only
  bf16x8 sR[4];      // B-stage regs (one chunk = 4 x 16B per thread)

#define ALOAD(st) {                                                           \
    aR[(st) % 4][0] = *(const float4*)(Ap + (st) * 32);                       \
    aR[(st) % 4][1] = *(const float4*)(Ap + (st) * 32 + 4); }

#define BLOAD(kc) { _Pragma("unroll")                                         \
    for (int i_ = 0; i_ < 4; i_++)                                            \
      sR[i_] = *(const bf16x8*)(Bsrc + (kc) * 128 + i_ * 8); }

#define BWRITE(kc) { _Pragma("unroll")                                        \
    for (int i_ = 0; i_ < 4; i_++)                                            \
      *(bf16x8*)(Bdst + ((kc) & 1) * CHUNKB_ +                                \
                 (((bq * 4 + i_) ^ (brow & 7)) * 16)) = sR[i_]; }

  // one K-step of 32: prefetch A(st+3), cvt A(st), 16 swizzled ds_read, 16 MFMA
#define KSTEP(st) {                                                           \
    if ((st) + 3 < 24) ALOAD((st) + 3)                                        \
    const bf16x8 af = cvt8(aR[(st) % 4][0], aR[(st) % 4][1]);                 \
    const char* bb = smem + (((st) >> 2) & 1) * CHUNKB_ + c * 256 +           \
                     (((((st) & 3) * 4 + q) ^ (c & 7)) * 16);                 \
    bf16x8 bfr[8];                                                            \
    _Pragma("unroll")                                                         \
    for (int j = 0; j < 8; j++) bfr[j] = *(const bf16x8*)(bb + j * 4096);     \
    _Pragma("unroll")                                                         \
    for (int j = 0; j < 8; j++)                                               \
      acc[j] = __builtin_amdgcn_mfma_f32_16x16x32_bf16(af, bfr[j], acc[j], 0, 0, 0); \
    _Pragma("unroll")                                                         \
    for (int j = 0; j < 8; j++) bfr[j] = *(const bf16x8*)(bb + 32768 + j * 4096); \
    _Pragma("unroll")                                                         \
    for (int j = 0; j < 8; j++)                                               \
      acc[8 + j] = __builtin_amdgcn_mfma_f32_16x16x32_bf16(af, bfr[j], acc[8 + j], 0, 0, 0); \
  }

  // chunk boundary: publish next B chunk, refill stage regs, raw barrier.
  // lgkmcnt-only (NO vmcnt drain): A-loads stay in flight across barriers.
#define BOUNDARY(cn) {                                                        \
    BWRITE((cn) + 1)                                                          \
    if ((cn) < 4) BLOAD((cn) + 2)                                             \
    asm volatile("s_waitcnt lgkmcnt(0)" ::: "memory");                        \
    __builtin_amdgcn_s_barrier(); }

  // prologue
  ALOAD(0) ALOAD(1) ALOAD(2)
  BLOAD(0)
  BWRITE(0)
  BLOAD(1)
  asm volatile("s_waitcnt lgkmcnt(0)" ::: "memory");
  __builtin_amdgcn_s_barrier();

  KSTEP(0)  KSTEP(1)  KSTEP(2)  KSTEP(3)  BOUNDARY(0)
  KSTEP(4)  KSTEP(5)  KSTEP(6)  KSTEP(7)  BOUNDARY(1)
  KSTEP(8)  KSTEP(9)  KSTEP(10) KSTEP(11) BOUNDARY(2)
  KSTEP(12) KSTEP(13) KSTEP(14) KSTEP(15) BOUNDARY(3)
  KSTEP(16) KSTEP(17) KSTEP(18) KSTEP(19) BOUNDARY(4)
  KSTEP(20) KSTEP(21) KSTEP(22) KSTEP(23)

#undef ALOAD
#undef BLOAD
#undef BWRITE
#undef KSTEP
#undef BOUNDARY

  // epilogue: bias + relu, store bf16 (tensor 0), column sums -> atomicAdd
#pragma unroll
  for (int j = 0; j < 16; j++) {
    const int n = j * 16 + c;
    const float bias = mlp_b[n];
    float colsum = 0.f;
    const int mb = m0 + wave * 16 + q * 4;
#pragma unroll
    for (int r = 0; r < 4; r++) {
      float v = acc[j][r] + bias;
      v = fmaxf(v, 0.f);
      colsum += v;
      if (tensor == 0) o1[(size_t)(mb + r) * H_ + n] = (__bf16)v;
    }
    colsum += __shfl_down(colsum, 32);
    colsum += __shfl_down(colsum, 16);
    if (lane < 16)
      atomicAdd(&dsum[bidx * H_ + j * 16 + lane], colsum);
  }
}

// logits: one s-row per wave. grid (129, B): s = bx*4+wave, rows 0..511 from o1,
// row 512 from o1_doc. lg[b,s] = dot(o1_row, o2_doc)
__global__ __launch_bounds__(256) void logits_kernel(
    const __bf16* __restrict__ o1, const float* __restrict__ sum1,
    const float* __restrict__ sum2, float* __restrict__ lg)
{
  const int b = blockIdx.y;
  const int t = threadIdx.x, lane = t & 63, wave = t >> 6;
  const int s = blockIdx.x * 4 + wave;
  if (s > 512) return;
  const float sc = 1.f / 512.f;
  const float4 w4 = ((const float4*)&sum2[b * H_])[lane];
  float p;
  if (s < 512) {
    const bf16x4 x = ((const bf16x4*)&o1[((size_t)b * S_ + s) * H_])[lane];
    p = ((float)x[0] * w4.x + (float)x[1] * w4.y +
         (float)x[2] * w4.z + (float)x[3] * w4.w) * sc;
  } else {
    const float4 x = ((const float4*)&sum1[b * H_])[lane];
    p = (x.x * w4.x + x.y * w4.y + x.z * w4.z + x.w * w4.w) * sc * sc;
  }
  p += __shfl_down(p, 32); p += __shfl_down(p, 16); p += __shfl_down(p, 8);
  p += __shfl_down(p, 4);  p += __shfl_down(p, 2);  p += __shfl_down(p, 1);
  if (lane == 0) lg[b * 513 + s] = p;
}

// fused: MLP head (row 512 of att) + softmax over 513 logits (rows 0..511)
__global__ __launch_bounds__(256) void softmax_head_kernel(
    const float* __restrict__ lg, const float* __restrict__ sum1, const float* __restrict__ sum2,
    const float* __restrict__ fd_w, const float* __restrict__ fd_b,
    const float* __restrict__ ff_w, const float* __restrict__ ff_b,
    float* __restrict__ out)
{
  const int b = blockIdx.x, t = threadIdx.x, lane = t & 63, wave = t >> 6;
  __shared__ __align__(16) float dc[512];
  __shared__ float sl[513];
  __shared__ float red[4], r1[4], r2[4];

  // --- head: h = relu(fd_w @ cat(o1_doc,o2_doc) + fd_b); out[512,b] = sigmoid(ff_w.h + ff_b)
  dc[t]       = sum1[b * H_ + t] * (1.f / 512.f);
  dc[t + 256] = sum2[b * H_ + t] * (1.f / 512.f);
  for (int i = t; i < 513; i += 256) sl[i] = lg[b * 513 + i];
  __syncthreads();
  const float4* wrow = (const float4*)&fd_w[(size_t)t * 512];
  const float4* dc4  = (const float4*)dc;
  float a0 = 0.f, a1 = 0.f;
#pragma unroll 8
  for (int k = 0; k < 128; k += 2) {
    const float4 w0 = wrow[k],     d0 = dc4[k];
    const float4 w1 = wrow[k + 1], d1 = dc4[k + 1];
    a0 += w0.x * d0.x + w0.y * d0.y + w0.z * d0.z + w0.w * d0.w;
    a1 += w1.x * d1.x + w1.y * d1.y + w1.z * d1.z + w1.w * d1.w;
  }
  const float h = fmaxf(a0 + a1 + fd_b[t], 0.f);
  float part = ff_w[t] * h;
  part += __shfl_down(part, 32); part += __shfl_down(part, 16);
  part += __shfl_down(part, 8);  part += __shfl_down(part, 4);
  part += __shfl_down(part, 2);  part += __shfl_down(part, 1);
  if (lane == 0) red[wave] = part;

  // --- softmax over sl[0..512]
  float m = -1e30f;
  for (int i = t; i < 513; i += 256) m = fmaxf(m, sl[i]);
  m = fmaxf(m, __shfl_down(m, 32)); m = fmaxf(m, __shfl_down(m, 16));
  m = fmaxf(m, __shfl_down(m, 8));  m = fmaxf(m, __shfl_down(m, 4));
  m = fmaxf(m, __shfl_down(m, 2));  m = fmaxf(m, __shfl_down(m, 1));
  if (lane == 0) r1[wave] = m;
  __syncthreads();
  m = fmaxf(fmaxf(r1[0], r1[1]), fmaxf(r1[2], r1[3]));
  float psum = 0.f;
  for (int i = t; i < 513; i += 256) { const float e = expf(sl[i] - m); sl[i] = e; psum += e; }
  psum += __shfl_down(psum, 32); psum += __shfl_down(psum, 16); psum += __shfl_down(psum, 8);
  psum += __shfl_down(psum, 4);  psum += __shfl_down(psum, 2);  psum += __shfl_down(psum, 1);
  if (lane == 0) r2[wave] = psum;
  __syncthreads();
  const float inv = 1.f / (r2[0] + r2[1] + r2[2] + r2[3]);
  for (int s = t; s < 512; s += 256) out[s * 64 + b] = sl[s] * inv;
  if (t == 0) {
    const float tot = red[0] + red[1] + red[2] + red[3] + ff_b[0];
    out[(size_t)512 * 64 + b] = 1.f / (1.f + expf(-tot));
  }
}

extern "C" void kernel_launch(void* const* d_in, const int* in_sizes, int n_in,
                              void* d_out, int out_size, void* d_ws, size_t ws_size,
                              hipStream_t stream) {
  const float* out1  = (const float*)d_in[0];
  const float* out2  = (const float*)d_in[1];
  const float* mlp_w = (const float*)d_in[2];
  const float* mlp_b = (const float*)d_in[3];
  const float* fd_w  = (const float*)d_in[4];
  const float* fd_b  = (const float*)d_in[5];
  const float* ff_w  = (const float*)d_in[6];
  const float* ff_b  = (const float*)d_in[7];
  float* out = (float*)d_out;

  __bf16* o1  = (__bf16*)d_ws;                       // 32768*256 bf16 = 16.78 MB
  __bf16* wbf = o1 + (size_t)M_ * H_;                // 256*768 bf16
  float*  s1  = (float*)(wbf + (size_t)H_ * VEC_);   // 64*256 f32
  float*  s2  = s1 + B_ * H_;                        // 64*256 f32
  float*  lgw = s2 + B_ * H_;                        // 64*513 f32

  prep_kernel<<<224, 256, 0, stream>>>(mlp_w, wbf, s1);
  gemm_doc_kernel<<<dim3(128, 2), 1024, 0, stream>>>(out1, out2, wbf, mlp_b, o1, s1, s2);
  logits_kernel<<<dim3(129, B_), 256, 0, stream>>>(o1, s1, s2, lgw);
  softmax_head_kernel<<<B_, 256, 0, stream>>>(lgw, s1, s2, fd_w, fd_b, ff_w, ff_b, out);
}